// Round 3
// baseline (259.934 us; speedup 1.0000x reference)
//
#include <hip/hip_runtime.h>
#include <hip/hip_bf16.h>

#define CDIM 128
#define EDIM 16
#define NEG_SLOPE 0.2f

typedef __attribute__((ext_vector_type(8))) short bf16x8;
typedef __attribute__((ext_vector_type(4))) float f32x4;
typedef unsigned int uint;
typedef unsigned short ushort;

__device__ __forceinline__ ushort f2bf(float f) {
    uint u = __float_as_uint(f);
    return (ushort)((u + 0x7fffu + ((u >> 16) & 1u)) >> 16);
}
__device__ __forceinline__ uint packbf(float lo, float hi) {
    return ((uint)f2bf(hi) << 16) | (uint)f2bf(lo);
}
__device__ __forceinline__ float bflo(uint w) { return __uint_as_float(w << 16); }
__device__ __forceinline__ float bfhi(uint w) { return __uint_as_float(w & 0xffff0000u); }

// ---------------- prep: dtype flags for `reducible` + in-degree histogram ----------------
__global__ void prep_kernel(const uint* __restrict__ red, int nwords, int* __restrict__ flags,
                            const int* __restrict__ dst, int* __restrict__ cnt, int E) {
    int i = blockIdx.x * 256 + threadIdx.x;
    if (i < nwords) {
        uint w = red[i];
        bool isInt = (w <= 1u);
        bool isFloat = (w == 0u) || (w == 0x3f800000u);
        if (!isInt) atomicOr(&flags[0], 1);
        if (!isFloat) atomicOr(&flags[1], 1);
    }
    if (i < E) atomicAdd(&cnt[dst[i]], 1);
}

// ---------------- BcatT[c][k] bf16 (transposed) + w_e scalars ----------------
// col layout: 0-127 x_r, 128-255 x_i, 256-383 res_r, 384-511 res_i
__global__ void bcatwe_kernel(const float* __restrict__ Wr, const float* __restrict__ Wi,
                              const float* __restrict__ Wrr, const float* __restrict__ Wri,
                              ushort* __restrict__ BT,
                              const float* __restrict__ WeR, const float* __restrict__ aeR,
                              const float* __restrict__ WeI, const float* __restrict__ aeI,
                              float* __restrict__ we) {
    if (blockIdx.x < 256) {
        int idx = blockIdx.x * 256 + threadIdx.x;
        int c = idx >> 7, k = idx & 127;
        const float* srcm;
        if (c < 128)      srcm = Wr;
        else if (c < 256) srcm = Wi;
        else if (c < 384) srcm = Wrr;
        else              srcm = Wri;
        BT[idx] = f2bf(srcm[k * 128 + (c & 127)]);
    } else {
        int lane = threadIdx.x;
        if (lane < 16) {
            float s = 0.f;
            for (int c = 0; c < CDIM; ++c) s += WeR[lane * CDIM + c] * aeR[c];
            we[lane] = s;
        } else if (lane < 32) {
            int j = lane - 16;
            float s = 0.f;
            for (int c = 0; c < CDIM; ++c) s += WeI[j * CDIM + c] * aeI[c];
            we[16 + j] = s;
        }
    }
}

// ---------------- fused MFMA GEMM: xcat[M][512](bf16) = h(f32)[M][128] @ Bcat ----------------
// B fully LDS-resident (128KB); A 64-row tile reg-staged from f32 with swizzled ds_write.
// 512 threads = 8 waves; wave w computes rows 0..63 x cols [w*64, w*64+64).
__global__ __launch_bounds__(512) void gemm_fused(const float* __restrict__ h,
                                                  const ushort* __restrict__ BT,
                                                  ushort* __restrict__ C, int M) {
    __shared__ ushort Bs[512 * 128];   // 128 KiB
    __shared__ ushort As[64 * 128];    // 16 KiB
    int t = threadIdx.x, lane = t & 63, wv = t >> 6;
    int rb = blockIdx.x * 64;
    int l15 = lane & 15, l4 = lane >> 4;

    // stage B: 128 groups of 4 cols (1KB each), pre-swizzled source chunk
#pragma unroll
    for (int p = 0; p < 16; ++p) {
        int g = wv * 16 + p;
        int col = g * 4 + l4;
        int chs = l15 ^ (col & 7);
        const ushort* gb = BT + col * 128 + chs * 8;
        __builtin_amdgcn_global_load_lds(
            (const __attribute__((address_space(1))) void*)gb,
            (__attribute__((address_space(3))) void*)((char*)Bs + g * 1024), 16, 0, 0);
    }

    // stage A: f32 -> bf16, swizzled ds_write_b128
    {
        int row = t >> 3, cp = (t & 7) * 2;   // row 0..63, two 16B chunks
        int gr = rb + row; if (gr > M - 1) gr = M - 1;
        const float4* hp = (const float4*)(h + (size_t)gr * 128 + cp * 8);
        float4 v0 = hp[0], v1 = hp[1], v2 = hp[2], v3 = hp[3];
        uint4 u0, u1;
        u0.x = packbf(v0.x, v0.y); u0.y = packbf(v0.z, v0.w);
        u0.z = packbf(v1.x, v1.y); u0.w = packbf(v1.z, v1.w);
        u1.x = packbf(v2.x, v2.y); u1.y = packbf(v2.z, v2.w);
        u1.z = packbf(v3.x, v3.y); u1.w = packbf(v3.z, v3.w);
        *(uint4*)((char*)As + row * 256 + ((cp)     ^ (row & 7)) * 16) = u0;
        *(uint4*)((char*)As + row * 256 + ((cp + 1) ^ (row & 7)) * 16) = u1;
    }
    __syncthreads();

    f32x4 acc[4][4];
#pragma unroll
    for (int i = 0; i < 4; ++i)
#pragma unroll
        for (int j = 0; j < 4; ++j) acc[i][j] = (f32x4){0.f, 0.f, 0.f, 0.f};

    const char* Ab = (const char*)As;
    const char* Bb = (const char*)Bs;
#pragma unroll
    for (int ks = 0; ks < 4; ++ks) {
        bf16x8 a[4], b[4];
#pragma unroll
        for (int f = 0; f < 4; ++f) {
            int row = f * 16 + l15;
            int ch = (ks * 4 + l4) ^ (row & 7);
            a[f] = *(const bf16x8*)(Ab + row * 256 + ch * 16);
            int col = wv * 64 + f * 16 + l15;
            int ch2 = (ks * 4 + l4) ^ (col & 7);
            b[f] = *(const bf16x8*)(Bb + col * 256 + ch2 * 16);
        }
#pragma unroll
        for (int i = 0; i < 4; ++i)
#pragma unroll
            for (int j = 0; j < 4; ++j)
                acc[i][j] = __builtin_amdgcn_mfma_f32_16x16x32_bf16(a[i], b[j], acc[i][j], 0, 0, 0);
    }

#pragma unroll
    for (int i = 0; i < 4; ++i) {
#pragma unroll
        for (int j = 0; j < 4; ++j) {
            int col = wv * 64 + j * 16 + l15;
#pragma unroll
            for (int r = 0; r < 4; ++r) {
                int gr = rb + i * 16 + l4 * 4 + r;
                if (gr < M) C[(size_t)gr * 512 + col] = f2bf(acc[i][j][r]);
            }
        }
    }
}

// ---------------- per-node attention dots (xcat is bf16) ----------------
__global__ __launch_bounds__(256) void adots_kernel(const ushort* __restrict__ xcat,
                                                    const float* __restrict__ attsr, const float* __restrict__ attdr,
                                                    const float* __restrict__ attsi, const float* __restrict__ attdi,
                                                    float* __restrict__ asr, float* __restrict__ adr,
                                                    float* __restrict__ asi, float* __restrict__ adi, int n) {
    int node = blockIdx.x * 4 + (threadIdx.x >> 6);
    int lane = threadIdx.x & 63;
    if (node >= n) return;
    const uint* xr = (const uint*)(xcat + (size_t)node * 512);
    uint wr_ = xr[lane];
    uint wi_ = xr[64 + lane];
    float r0 = bflo(wr_), r1 = bfhi(wr_);
    float i0 = bflo(wi_), i1 = bfhi(wi_);
    float2 sr = ((const float2*)attsr)[lane], dr = ((const float2*)attdr)[lane];
    float2 si = ((const float2*)attsi)[lane], di = ((const float2*)attdi)[lane];
    float s0 = r0 * sr.x + r1 * sr.y;
    float s1 = r0 * dr.x + r1 * dr.y;
    float s2 = i0 * si.x + i1 * si.y;
    float s3 = i0 * di.x + i1 * di.y;
#pragma unroll
    for (int d = 32; d; d >>= 1) {
        s0 += __shfl_xor(s0, d); s1 += __shfl_xor(s1, d);
        s2 += __shfl_xor(s2, d); s3 += __shfl_xor(s3, d);
    }
    if (lane == 0) { asr[node] = s0; adr[node] = s1; asi[node] = s2; adi[node] = s3; }
}

// ---------------- exclusive scan (single block, chunked) ----------------
__global__ __launch_bounds__(1024) void scan_kernel(const int* __restrict__ cnt, int* __restrict__ offv,
                                                    int* __restrict__ cursor, int n) {
    __shared__ int wsum[16];
    __shared__ int s_carry;
    int t = threadIdx.x, lane = t & 63, wid = t >> 6;
    if (t == 0) s_carry = 0;
    __syncthreads();
    for (int base = 0; base < n; base += 4096) {
        int i0 = base + t * 4;
        int v[4];
#pragma unroll
        for (int j = 0; j < 4; ++j) { int i = i0 + j; v[j] = (i < n) ? cnt[i] : 0; }
        int s = v[0] + v[1] + v[2] + v[3];
        int incl = s;
#pragma unroll
        for (int d = 1; d < 64; d <<= 1) { int u = __shfl_up(incl, d); if (lane >= d) incl += u; }
        if (lane == 63) wsum[wid] = incl;
        __syncthreads();
        int carry = s_carry;
        int wpre = 0;
        for (int w = 0; w < wid; ++w) wpre += wsum[w];
        int run = carry + wpre + (incl - s);
#pragma unroll
        for (int j = 0; j < 4; ++j) {
            int i = i0 + j;
            if (i < n) { offv[i] = run; cursor[i] = run; }
            run += v[j];
        }
        __syncthreads();
        if (t == 1023) s_carry = carry + wpre + incl;
        __syncthreads();
    }
    if (t == 0) offv[n] = s_carry;
}

// ---------------- edge pass: precompute alpha_pre + srcoff, scatter into CSR ----------------
__global__ void scatter_kernel(const int* __restrict__ src, const int* __restrict__ dst,
                               const float* __restrict__ ea, const float* __restrict__ we,
                               const void* __restrict__ red, const int* __restrict__ flags,
                               const float* __restrict__ asr, const float* __restrict__ asi,
                               int* __restrict__ cursor, float* __restrict__ esum,
                               uint* __restrict__ so_s, float* __restrict__ ap_s, int E) {
    int e = blockIdx.x * 256 + threadIdx.x;
    if (e >= E) return;
    int s = src[e], d = dst[e];
    const float4* row = (const float4*)(ea + (size_t)e * EDIM);
    float er = 0.f, ei = 0.f;
#pragma unroll
    for (int q = 0; q < 4; ++q) {
        float4 v = row[q];
        float4 wr = ((const float4*)we)[q];
        float4 wi = ((const float4*)we)[4 + q];
        er += v.x * wr.x + v.y * wr.y + v.z * wr.z + v.w * wr.w;
        ei += v.x * wi.x + v.y * wi.y + v.z * wi.z + v.w * wi.w;
    }
    int notInt = flags[0], notFloat = flags[1];
    bool rr;
    if (!notInt)        rr = ((const int*)red)[d] != 0;
    else if (!notFloat) rr = ((const float*)red)[d] != 0.f;
    else                rr = ((const unsigned char*)red)[d] != 0;

    float ev = rr ? er : ei;
    float a = (rr ? asr : asi)[s];
    int pos = atomicAdd(&cursor[d], 1);
    so_s[pos] = (uint)s * 1024u + (rr ? 0u : 256u);
    ap_s[pos] = a + ev;
    atomicAdd(&esum[d], ev);
}

// ---------------- node kernel: online softmax + gather + residual + select + relu ----------------
__global__ __launch_bounds__(256) void node_kernel(
    const ushort* __restrict__ xcat,
    const float* __restrict__ adst_r, const float* __restrict__ adst_i,
    const float* __restrict__ asrc_r, const float* __restrict__ asrc_i,
    const void* __restrict__ red, const int* __restrict__ flags,
    const int* __restrict__ offv, const uint* __restrict__ so_s,
    const float* __restrict__ ap_s, const float* __restrict__ esum,
    const float* __restrict__ bias_r, const float* __restrict__ bias_i,
    float* __restrict__ out, int n) {
    __shared__ uint2 buf[4][64];
    int wv = threadIdx.x >> 6, lane = threadIdx.x & 63;
    int node = blockIdx.x * 4 + wv;
    if (node >= n) return;

    int notInt = flags[0], notFloat = flags[1];
    bool r;
    if (!notInt)        r = ((const int*)red)[node] != 0;
    else if (!notFloat) r = ((const float*)red)[node] != 0.f;
    else                r = ((const unsigned char*)red)[node] != 0;

    float adst = (r ? adst_r : adst_i)[node];
    int b0 = offv[node], b1 = offv[node + 1];
    int k = b1 - b0;
    const char* xb = (const char*)xcat;

    float m = -1e30f, denom = 0.f;
    float acc0 = 0.f, acc1 = 0.f;

    for (int base = b0; base < b1; base += 64) {
        int j = base + lane;
        float ap = -1e30f; uint soff = 0;
        if (j < b1) { soff = so_s[j]; ap = ap_s[j]; }
        float al = ap + adst;
        al = (al >= 0.f) ? al : NEG_SLOPE * al;
        float cm = al;
#pragma unroll
        for (int d = 32; d; d >>= 1) cm = fmaxf(cm, __shfl_xor(cm, d));
        float mn = fmaxf(m, cm);
        float sc = __expf(m - mn);
        denom *= sc; acc0 *= sc; acc1 *= sc;
        m = mn;
        float ex = __expf(al - mn);     // pads underflow to 0
        buf[wv][lane] = make_uint2(__float_as_uint(ex), soff);
        __builtin_amdgcn_wave_barrier();
        int cc = min(64, b1 - base);
        int ccp = (cc + 3) & ~3;
        for (int tq = 0; tq < ccp; tq += 4) {
#pragma unroll
            for (int q = 0; q < 4; ++q) {
                uint2 u = buf[wv][tq + q];
                float w = __uint_as_float(u.x);
                uint v = *(const uint*)(xb + u.y + lane * 4);
                acc0 += w * bflo(v); acc1 += w * bfhi(v);
            }
        }
        float exs = ex;
#pragma unroll
        for (int d = 32; d; d >>= 1) exs += __shfl_xor(exs, d);
        denom += exs;
        __builtin_amdgcn_wave_barrier();
    }

    // self loop
    float eself = esum[node] / fmaxf((float)k, 1.f);
    float asn = (r ? asrc_r : asrc_i)[node];
    float a = asn + adst + eself;
    float aself = (a >= 0.f) ? a : NEG_SLOPE * a;
    float mn = fmaxf(m, aself);
    float sc = __expf(m - mn);
    float exl = __expf(aself - mn);
    denom = denom * sc + exl;
    uint voff = (uint)node * 1024u + (r ? 0u : 256u);
    uint vsw = *(const uint*)(xb + voff + lane * 4);
    acc0 = acc0 * sc + exl * bflo(vsw);
    acc1 = acc1 * sc + exl * bfhi(vsw);

    float inv = 1.f / denom;
    uint roff = (uint)node * 1024u + (r ? 512u : 768u);
    uint bw = *(const uint*)(xb + roff + lane * 4);
    float2 bi2 = ((const float2*)(r ? bias_r : bias_i))[lane];
    float o0 = acc0 * inv + bflo(bw) + bi2.x;
    float o1 = acc1 * inv + bfhi(bw) + bi2.y;
    out[(size_t)node * 128 + lane * 2]     = fmaxf(o0, 0.f);
    out[(size_t)node * 128 + lane * 2 + 1] = fmaxf(o1, 0.f);
}

extern "C" void kernel_launch(void* const* d_in, const int* in_sizes, int n_in,
                              void* d_out, int out_size, void* d_ws, size_t ws_size,
                              hipStream_t stream) {
    const float* h          = (const float*)d_in[0];
    const int*   edge_index = (const int*)d_in[1];
    const float* edge_attr  = (const float*)d_in[2];
    const void*  reducible  = d_in[3];
    const float* red_W      = (const float*)d_in[4];
    const float* red_att_src= (const float*)d_in[5];
    const float* red_att_dst= (const float*)d_in[6];
    const float* red_W_edge = (const float*)d_in[7];
    const float* red_att_edge=(const float*)d_in[8];
    const float* red_W_res  = (const float*)d_in[9];
    const float* red_bias   = (const float*)d_in[10];
    const float* irr_W      = (const float*)d_in[11];
    const float* irr_att_src= (const float*)d_in[12];
    const float* irr_att_dst= (const float*)d_in[13];
    const float* irr_W_edge = (const float*)d_in[14];
    const float* irr_att_edge=(const float*)d_in[15];
    const float* irr_W_res  = (const float*)d_in[16];
    const float* irr_bias   = (const float*)d_in[17];

    const int N = in_sizes[0] / CDIM;
    const int E = in_sizes[1] / 2;
    const int* src = edge_index;
    const int* dst = edge_index + E;

    float* out = (float*)d_out;

    size_t cur = 0;
    auto alloc = [&](size_t bytes) { size_t p = cur; cur = (cur + bytes + 255) & ~(size_t)255; return p; };
    char* ws = (char*)d_ws;
    size_t o_xcat  = alloc((size_t)N * 512 * 2);   // bf16 [x_r|x_i|res_r|res_i]
    size_t o_bcat  = alloc(512 * 128 * 2);         // bf16 transposed
    size_t o_we    = alloc(256);
    size_t o_asr   = alloc((size_t)N * 4);
    size_t o_adr   = alloc((size_t)N * 4);
    size_t o_asi   = alloc((size_t)N * 4);
    size_t o_adi   = alloc((size_t)N * 4);
    size_t o_flags = alloc(256);
    size_t o_cnt   = alloc((size_t)N * 4);
    size_t o_esum  = alloc((size_t)N * 4);         // contiguous after cnt (one memset)
    size_t o_off   = alloc((size_t)(N + 1) * 4);
    size_t o_cur   = alloc((size_t)N * 4);
    size_t o_so    = alloc((size_t)E * 4);
    size_t o_ap    = alloc((size_t)E * 4);
    if (cur > ws_size) return;

    ushort* xcat = (ushort*)(ws + o_xcat);
    ushort* bcat = (ushort*)(ws + o_bcat);
    float* we    = (float*)(ws + o_we);
    float* asr   = (float*)(ws + o_asr);
    float* adr   = (float*)(ws + o_adr);
    float* asi   = (float*)(ws + o_asi);
    float* adi   = (float*)(ws + o_adi);
    int*   flags = (int*)(ws + o_flags);
    int*   cnt   = (int*)(ws + o_cnt);
    float* esum  = (float*)(ws + o_esum);
    int*   offv  = (int*)(ws + o_off);
    int*   curs  = (int*)(ws + o_cur);
    uint*  so_s  = (uint*)(ws + o_so);
    float* ap_s  = (float*)(ws + o_ap);

    hipMemsetAsync(flags, 0, 8, stream);
    hipMemsetAsync(cnt, 0, o_esum + (size_t)N * 4 - o_cnt, stream);  // cnt + esum

    int nwords = N / 4;
    prep_kernel<<<(E + 255) / 256, 256, 0, stream>>>((const uint*)reducible, nwords, flags, dst, cnt, E);

    bcatwe_kernel<<<257, 256, 0, stream>>>(red_W, irr_W, red_W_res, irr_W_res, bcat,
                                           red_W_edge, red_att_edge, irr_W_edge, irr_att_edge, we);

    gemm_fused<<<(N + 63) / 64, 512, 0, stream>>>(h, bcat, xcat, N);

    adots_kernel<<<(N + 3) / 4, 256, 0, stream>>>(xcat, red_att_src, red_att_dst,
                                                  irr_att_src, irr_att_dst, asr, adr, asi, adi, N);

    scan_kernel<<<1, 1024, 0, stream>>>(cnt, offv, curs, N);

    scatter_kernel<<<(E + 255) / 256, 256, 0, stream>>>(src, dst, edge_attr, we,
                                                        reducible, flags, asr, asi,
                                                        curs, esum, so_s, ap_s, E);

    node_kernel<<<(N + 3) / 4, 256, 0, stream>>>(xcat, adr, adi, asr, asi,
                                                 reducible, flags, offv, so_s, ap_s, esum,
                                                 red_bias, irr_bias, out, N);
}